// Round 11
// baseline (150.516 us; speedup 1.0000x reference)
//
#include <hip/hip_runtime.h>
#include <hip/hip_bf16.h>

#define B_   16
#define N_   1024
#define INF_ 256
#define NH_  4
#define HD_  256
#define L2E  1.4426950408889634f

typedef __attribute__((ext_vector_type(8))) short short8;
typedef __attribute__((ext_vector_type(4))) float f32x4;

__device__ __forceinline__ float bf2f(unsigned short u) {
    union { unsigned int i; float f; } v; v.i = ((unsigned int)u) << 16; return v.f;
}
__device__ __forceinline__ unsigned short f2bf(float f) {
    union { float f; unsigned int i; } v; v.f = f;
    unsigned int x = v.i;
    return (unsigned short)((x + 0x7fffu + ((x >> 16) & 1u)) >> 16);
}
// pack 2 f32 -> 2 bf16 in one op (low16 = lo, high16 = hi); no builtin on gfx950
__device__ __forceinline__ unsigned int cvt_pk_bf16(float lo, float hi) {
    unsigned int r;
    asm("v_cvt_pk_bf16_f32 %0, %1, %2" : "=v"(r) : "v"(lo), "v"(hi));
    return r;
}

// ---------------------------------------------------------------------------
// Kernel PREP (fused):
//  blocks [0,2048): pack adj -> TRANSPOSED bitmask pb[word][grow] (uint32,
//    bit p of word w = adj[row][w*32+p]); k_attn mask loads are coalesced.
//  blocks [2048,2080): W fp32 -> wswz bf16 in MFMA B-frag order.
// ~11us floor (67MB adj read, HBM-bound) — left unchanged.
// ---------------------------------------------------------------------------
__global__ __launch_bounds__(256) void k_prep(const int* __restrict__ adj,
                                              const float* __restrict__ W,
                                              unsigned int* __restrict__ pb,
                                              unsigned short* __restrict__ wswz)
{
    int bx = blockIdx.x, t = threadIdx.x;
    if (bx < 2048) {
        int wave = t >> 6, lane = t & 63;
        int row = bx * 8 + wave * 2 + (lane >> 5);   // [0, 16384)
        int w   = lane & 31;
        const int4* ar = (const int4*)(adj + ((long)row << 10) + w * 32);
        unsigned int u = 0;
        #pragma unroll
        for (int k = 0; k < 8; k++) {
            int4 a = ar[k];
            u |= ((unsigned)a.x) << (4 * k);
            u |= ((unsigned)a.y) << (4 * k + 1);
            u |= ((unsigned)a.z) << (4 * k + 2);
            u |= ((unsigned)a.w) << (4 * k + 3);
        }
        pb[((long)w << 14) + row] = u;               // TRANSPOSED: [word][grow]
    } else {
        int slot = (bx - 2048) * 256 + t;
        int kstep = slot >> 10;
        int nt    = (slot >> 6) & 15;
        int lane  = slot & 63;
        int k0 = kstep * 32 + (lane >> 4) * 8;
        int n  = nt * 16 + (lane & 15);
        ushort4 o0, o1;
        o0.x = f2bf(W[(k0 + 0) * HD_ + n]);
        o0.y = f2bf(W[(k0 + 1) * HD_ + n]);
        o0.z = f2bf(W[(k0 + 2) * HD_ + n]);
        o0.w = f2bf(W[(k0 + 3) * HD_ + n]);
        o1.x = f2bf(W[(k0 + 4) * HD_ + n]);
        o1.y = f2bf(W[(k0 + 5) * HD_ + n]);
        o1.z = f2bf(W[(k0 + 6) * HD_ + n]);
        o1.w = f2bf(W[(k0 + 7) * HD_ + n]);
        *(ushort4*)&wswz[(long)slot * 8]     = o0;
        *(ushort4*)&wswz[(long)slot * 8 + 4] = o1;
    }
}

// ---------------------------------------------------------------------------
// Kernel A: h = x @ W via MFMA — 64-ROW BLOCKS for 4x B-frag reuse (R10,
// neutral vs R9 but lower L2 traffic; kept).
// grid 256 x 256 thr (4 waves, one head each), 64 rows; per ks the 4
// B-frags load ONCE into regs, reused across 4 row-groups.
// Emits hswz (B-frag order bf16) + per-row factors:
//   esr[(b,h,i)]  = exp2(-0.8*ss)   (E1 cancels in softmax -> dropped)
//   edst[(b,h,j)] = {exp2(sd), exp2(0.2*sd)}
// ---------------------------------------------------------------------------
__global__ __launch_bounds__(256, 4) void k_gemm_h(
    const float* __restrict__ x, const float* __restrict__ a,
    const unsigned short* __restrict__ wswz,
    unsigned short* __restrict__ hswz,
    float* __restrict__ esr, float2* __restrict__ edst)
{
    __shared__ unsigned short xls[64][264];
    int t = threadIdx.x;
    int blk = blockIdx.x;            // 256 blocks
    int row0 = blk * 64;
    int b  = blk >> 4;
    int n0 = row0 & 1023;

    {
        int sr0 = t >> 4, sc = (t & 15) * 16;
        #pragma unroll
        for (int rr = 0; rr < 4; rr++) {
            int sr = sr0 + rr * 16;
            const float* xp = x + (long)(row0 + sr) * INF_ + sc;
            float4 v0 = ((const float4*)xp)[0];
            float4 v1 = ((const float4*)xp)[1];
            float4 v2 = ((const float4*)xp)[2];
            float4 v3 = ((const float4*)xp)[3];
            ushort4 u0 = {f2bf(v0.x), f2bf(v0.y), f2bf(v0.z), f2bf(v0.w)};
            ushort4 u1 = {f2bf(v1.x), f2bf(v1.y), f2bf(v1.z), f2bf(v1.w)};
            ushort4 u2 = {f2bf(v2.x), f2bf(v2.y), f2bf(v2.z), f2bf(v2.w)};
            ushort4 u3 = {f2bf(v3.x), f2bf(v3.y), f2bf(v3.z), f2bf(v3.w)};
            *(ushort4*)&xls[sr][sc]      = u0;
            *(ushort4*)&xls[sr][sc + 4]  = u1;
            *(ushort4*)&xls[sr][sc + 8]  = u2;
            *(ushort4*)&xls[sr][sc + 12] = u3;
        }
    }
    __syncthreads();

    int wave = t >> 6, lane = t & 63, quad = lane >> 4, l15 = lane & 15;
    f32x4 acc[4][4];   // [rowgroup][nt] — all indices compile-time constant
    #pragma unroll
    for (int rg = 0; rg < 4; rg++)
        #pragma unroll
        for (int nt = 0; nt < 4; nt++) acc[rg][nt] = (f32x4){0.f, 0.f, 0.f, 0.f};

    #pragma unroll
    for (int ks = 0; ks < 8; ks++) {
        short8 bfr[4];
        #pragma unroll
        for (int nt = 0; nt < 4; nt++)
            bfr[nt] = *(const short8*)(wswz +
                ((long)((ks * 16 + wave * 4 + nt) * 64 + lane)) * 8);
        #pragma unroll
        for (int rg = 0; rg < 4; rg++) {
            short8 af = *(const short8*)&xls[rg * 16 + l15][ks * 32 + quad * 8];
            #pragma unroll
            for (int nt = 0; nt < 4; nt++)
                acc[rg][nt] = __builtin_amdgcn_mfma_f32_16x16x32_bf16(
                    af, bfr[nt], acc[rg][nt], 0, 0, 0);
        }
    }

    // hswz store (B-frag order for k_attn), per rowgroup
    int q0 = (quad & 1) * 4;
    #pragma unroll
    for (int rg = 0; rg < 4; rg++) {
        int row0g = row0 + rg * 16;
        int qd = ((row0g & 31) + quad * 4) >> 3;
        long bj32 = row0g >> 5;
        #pragma unroll
        for (int nt = 0; nt < 4; nt++) {
            int dg = wave * 4 + nt;
            long idx8 = (bj32 * 16 + dg) * 64 + qd * 16 + l15;
            ushort4 o = {f2bf(acc[rg][nt][0]), f2bf(acc[rg][nt][1]),
                         f2bf(acc[rg][nt][2]), f2bf(acc[rg][nt][3])};
            *(ushort4*)&hswz[idx8 * 8 + q0] = o;
        }
    }

    // fused scores -> row factor + exp pairs, pre-scaled by log2(e)
    float as_[4], ad_[4];
    #pragma unroll
    for (int nt = 0; nt < 4; nt++) {
        int d = nt * 16 + l15;
        as_[nt] = a[d * NH_ + wave];
        ad_[nt] = a[(64 + d) * NH_ + wave];
    }
    #pragma unroll
    for (int rg = 0; rg < 4; rg++) {
        #pragma unroll
        for (int r = 0; r < 4; r++) {
            float ps = acc[rg][0][r] * as_[0] + acc[rg][1][r] * as_[1]
                     + acc[rg][2][r] * as_[2] + acc[rg][3][r] * as_[3];
            float pd = acc[rg][0][r] * ad_[0] + acc[rg][1][r] * ad_[1]
                     + acc[rg][2][r] * ad_[2] + acc[rg][3][r] * ad_[3];
            #pragma unroll
            for (int m = 1; m < 16; m <<= 1) {
                ps += __shfl_xor(ps, m);
                pd += __shfl_xor(pd, m);
            }
            if (l15 == 0) {
                int row = n0 + rg * 16 + quad * 4 + r;
                float s1 = ps * L2E, s2 = pd * L2E;
                esr[((long)b * NH_ + wave) * N_ + row] = __builtin_exp2f(-0.8f * s1);
                edst[((long)b * NH_ + wave) * N_ + row] =
                    make_float2(__builtin_exp2f(s2), __builtin_exp2f(0.2f * s2));
            }
        }
    }
}

// ---------------------------------------------------------------------------
// Kernel C: masked softmax + MFMA aggregate — HIGH REUSE + HIGH TLP.
// R9/R10 ran 1 block/CU = 4 waves/SIMD: every load + the serial VALU
// chain hidden by only 4 waves -> ~15% issue efficiency. R6's TLP failure
// had NO head-grouping (512KB hswz/block); this keeps the 128KB head
// slice AND doubles wave supply: 128-row groups, grid 512 x 512 thr
// (8 waves x 16 rows), same per-wave body (R6-measured 60 VGPR at
// (512,4) => <=64 => 4 blocks/CU = 32 waves/CU = 8 waves/SIMD).
// Per-jc live hswz set = 4KB x 4 blocks = 16KB < 32KB L1, so the
// 8x-per-line within-block reuse still L1-hits. hswz L2 traffic 64MB.
// No jh split -> no cross-wave combine/barriers. edst head-slice (8KB)
// staged once to LDS. pb transposed -> coalesced.
// __launch_bounds__(512,4) = cap 128, floor 2 blocks/CU (NEVER min>=8:
// R2/R3 VGPR collapse).
// ---------------------------------------------------------------------------
__global__ __launch_bounds__(512, 4) void k_attn(
    const unsigned int* __restrict__ pb, const unsigned short* __restrict__ hswz,
    const float* __restrict__ esr, const float2* __restrict__ edst,
    float* __restrict__ out)
{
    __shared__ float2 esb[1024];   // 8 KB: edst slice for (b, hh)
    __shared__ uint2 mtab[16];

    int t = threadIdx.x;
    int bid = blockIdx.x;
    int swz = (bid & 7) * 64 + (bid >> 3);   // bijective (512 % 8 == 0)
    int b  = swz >> 5;                        // 2 b per XCD -> L2-resident
    int hh = (swz >> 3) & 3;
    int rg = swz & 7;
    int row0 = rg * 128;

    int wave = t >> 6, lane = t & 63, quad = lane >> 4, l15 = lane & 15;

    esb[t]       = edst[((long)(b * NH_ + hh)) * N_ + t];
    esb[t + 512] = edst[((long)(b * NH_ + hh)) * N_ + t + 512];
    if (t < 16) {
        int k = t;
        unsigned int w0 = ((k & 1) ? 0xffffu : 0u) | ((k & 2) ? 0xffff0000u : 0u);
        unsigned int w1 = ((k & 4) ? 0xffffu : 0u) | ((k & 8) ? 0xffff0000u : 0u);
        mtab[k] = make_uint2(w0, w1);
    }
    __syncthreads();

    int irow = row0 + wave * 16 + l15;
    float r0 = esr[((long)(b * NH_ + hh)) * N_ + irow];
    // transposed pb: word jc at pb[jc*16384 + b*1024 + irow] (coalesced)
    const unsigned int* pbw = pb + ((long)b << 10) + irow;

    f32x4 acc[4], dn;
    #pragma unroll
    for (int i = 0; i < 4; i++) acc[i] = (f32x4){0.f, 0.f, 0.f, 0.f};
    dn = (f32x4){0.f, 0.f, 0.f, 0.f};
    short8 ones;
    #pragma unroll
    for (int i = 0; i < 8; i++) ones[i] = (short)0x3F80;   // bf16 1.0

    int shq = quad * 8;

    #pragma unroll 4
    for (int jc = 0; jc < 32; jc++) {
        unsigned int m0 = (pbw[((long)jc << 14)] >> shq) & 0xffu;
        const f32x4* ej = (const f32x4*)&esb[jc * 32 + quad * 8];

        union { unsigned int u[4]; short8 s; } p0;
        #pragma unroll
        for (int qp = 0; qp < 4; qp++) {
            f32x4 d = ej[qp];   // {D1_j, D2_j, D1_j', D2_j'} for j=2qp, 2qp+1
            p0.u[qp] = cvt_pk_bf16(fmaxf(d[0], r0 * d[1]), fmaxf(d[2], r0 * d[3]));
        }
        uint2 ma = mtab[m0 & 15u], mb = mtab[m0 >> 4];
        p0.u[0] &= ma.x; p0.u[1] &= ma.y; p0.u[2] &= mb.x; p0.u[3] &= mb.y;

        long s8 = ((long)(b * 32 + jc)) * 1024;
        #pragma unroll
        for (int idt = 0; idt < 4; idt++) {
            short8 bf = *(const short8*)(hswz + (s8 + (hh * 4 + idt) * 64 + lane) * 8);
            acc[idt] = __builtin_amdgcn_mfma_f32_16x16x32_bf16(p0.s, bf, acc[idt], 0, 0, 0);
        }
        dn = __builtin_amdgcn_mfma_f32_16x16x32_bf16(p0.s, ones, dn, 0, 0, 0);
    }

    // epilogue: per-wave normalize + store (no cross-wave combine at all)
    float inv[4];
    #pragma unroll
    for (int r = 0; r < 4; r++) inv[r] = 1.0f / dn[r];
    #pragma unroll
    for (int idt = 0; idt < 4; idt++) {
        int col = hh * 64 + idt * 16 + l15;
        #pragma unroll
        for (int r = 0; r < 4; r++) {
            long row_g = (long)b * N_ + row0 + wave * 16 + quad * 4 + r;
            out[row_g * HD_ + col] = acc[idt][r] * inv[r];
        }
    }
}

extern "C" void kernel_launch(void* const* d_in, const int* in_sizes, int n_in,
                              void* d_out, int out_size, void* d_ws, size_t ws_size,
                              hipStream_t stream) {
    const float* x   = (const float*)d_in[0];
    const int*   adj = (const int*)d_in[1];
    const float* W   = (const float*)d_in[2];
    const float* a   = (const float*)d_in[3];
    float* out = (float*)d_out;

    unsigned int* pb      = (unsigned int*)d_ws;                       // 2 MB
    unsigned short* hswz  = (unsigned short*)(pb + 524288);            // 8 MB
    unsigned short* wswz  = hswz + (long)B_ * N_ * HD_;                // 128 KB
    float* esr   = (float*)(wswz + INF_ * HD_);                        // 256 KB
    float2* edst = (float2*)(esr + (long)B_ * NH_ * N_);               // 512 KB

    k_prep<<<2080, 256, 0, stream>>>(adj, W, pb, wswz);
    k_gemm_h<<<256, 256, 0, stream>>>(x, a, wswz, hswz, esr, edst);
    k_attn<<<512, 512, 0, stream>>>(pb, hswz, esr, edst, out);
}

// Round 12
// 147.667 us; speedup vs baseline: 1.0193x; 1.0193x over previous
//
#include <hip/hip_runtime.h>
#include <hip/hip_bf16.h>

#define B_   16
#define N_   1024
#define INF_ 256
#define NH_  4
#define HD_  256
#define L2E  1.4426950408889634f

typedef __attribute__((ext_vector_type(8))) short short8;
typedef __attribute__((ext_vector_type(4))) float f32x4;

__device__ __forceinline__ float bf2f(unsigned short u) {
    union { unsigned int i; float f; } v; v.i = ((unsigned int)u) << 16; return v.f;
}
__device__ __forceinline__ unsigned short f2bf(float f) {
    union { float f; unsigned int i; } v; v.f = f;
    unsigned int x = v.i;
    return (unsigned short)((x + 0x7fffu + ((x >> 16) & 1u)) >> 16);
}
// pack 2 f32 -> 2 bf16 in one op (low16 = lo, high16 = hi); no builtin on gfx950
__device__ __forceinline__ unsigned int cvt_pk_bf16(float lo, float hi) {
    unsigned int r;
    asm("v_cvt_pk_bf16_f32 %0, %1, %2" : "=v"(r) : "v"(lo), "v"(hi));
    return r;
}

// ---------------------------------------------------------------------------
// Kernel PREP (fused):
//  blocks [0,2048): pack adj -> TRANSPOSED bitmask pb[word][grow] (uint32,
//    bit p of word w = adj[row][w*32+p]); k_attn mask loads are coalesced.
//  blocks [2048,2080): W fp32 -> wswz bf16 in MFMA B-frag order.
// ~11us floor (67MB adj read, HBM-bound) — at roofline, unchanged.
// ---------------------------------------------------------------------------
__global__ __launch_bounds__(256) void k_prep(const int* __restrict__ adj,
                                              const float* __restrict__ W,
                                              unsigned int* __restrict__ pb,
                                              unsigned short* __restrict__ wswz)
{
    int bx = blockIdx.x, t = threadIdx.x;
    if (bx < 2048) {
        int wave = t >> 6, lane = t & 63;
        int row = bx * 8 + wave * 2 + (lane >> 5);   // [0, 16384)
        int w   = lane & 31;
        const int4* ar = (const int4*)(adj + ((long)row << 10) + w * 32);
        unsigned int u = 0;
        #pragma unroll
        for (int k = 0; k < 8; k++) {
            int4 a = ar[k];
            u |= ((unsigned)a.x) << (4 * k);
            u |= ((unsigned)a.y) << (4 * k + 1);
            u |= ((unsigned)a.z) << (4 * k + 2);
            u |= ((unsigned)a.w) << (4 * k + 3);
        }
        pb[((long)w << 14) + row] = u;               // TRANSPOSED: [word][grow]
    } else {
        int slot = (bx - 2048) * 256 + t;
        int kstep = slot >> 10;
        int nt    = (slot >> 6) & 15;
        int lane  = slot & 63;
        int k0 = kstep * 32 + (lane >> 4) * 8;
        int n  = nt * 16 + (lane & 15);
        ushort4 o0, o1;
        o0.x = f2bf(W[(k0 + 0) * HD_ + n]);
        o0.y = f2bf(W[(k0 + 1) * HD_ + n]);
        o0.z = f2bf(W[(k0 + 2) * HD_ + n]);
        o0.w = f2bf(W[(k0 + 3) * HD_ + n]);
        o1.x = f2bf(W[(k0 + 4) * HD_ + n]);
        o1.y = f2bf(W[(k0 + 5) * HD_ + n]);
        o1.z = f2bf(W[(k0 + 6) * HD_ + n]);
        o1.w = f2bf(W[(k0 + 7) * HD_ + n]);
        *(ushort4*)&wswz[(long)slot * 8]     = o0;
        *(ushort4*)&wswz[(long)slot * 8 + 4] = o1;
    }
}

// ---------------------------------------------------------------------------
// Kernel A: h = x @ W via MFMA — 64-ROW BLOCKS for 4x B-frag reuse.
// grid 256 x 256 thr (4 waves, one head each), 64 rows; per ks the 4
// B-frags load ONCE into regs, reused across 4 row-groups.
// Emits hswz (B-frag order bf16) + per-row factors:
//   esr[(b,h,i)]  = exp2(-0.8*ss)   (E1 cancels in softmax -> dropped)
//   edst[(b,h,j)] = {exp2(sd), exp2(0.2*sd)}
// ---------------------------------------------------------------------------
__global__ __launch_bounds__(256, 4) void k_gemm_h(
    const float* __restrict__ x, const float* __restrict__ a,
    const unsigned short* __restrict__ wswz,
    unsigned short* __restrict__ hswz,
    float* __restrict__ esr, float2* __restrict__ edst)
{
    __shared__ unsigned short xls[64][264];
    int t = threadIdx.x;
    int blk = blockIdx.x;            // 256 blocks
    int row0 = blk * 64;
    int b  = blk >> 4;
    int n0 = row0 & 1023;

    {
        int sr0 = t >> 4, sc = (t & 15) * 16;
        #pragma unroll
        for (int rr = 0; rr < 4; rr++) {
            int sr = sr0 + rr * 16;
            const float* xp = x + (long)(row0 + sr) * INF_ + sc;
            float4 v0 = ((const float4*)xp)[0];
            float4 v1 = ((const float4*)xp)[1];
            float4 v2 = ((const float4*)xp)[2];
            float4 v3 = ((const float4*)xp)[3];
            ushort4 u0 = {f2bf(v0.x), f2bf(v0.y), f2bf(v0.z), f2bf(v0.w)};
            ushort4 u1 = {f2bf(v1.x), f2bf(v1.y), f2bf(v1.z), f2bf(v1.w)};
            ushort4 u2 = {f2bf(v2.x), f2bf(v2.y), f2bf(v2.z), f2bf(v2.w)};
            ushort4 u3 = {f2bf(v3.x), f2bf(v3.y), f2bf(v3.z), f2bf(v3.w)};
            *(ushort4*)&xls[sr][sc]      = u0;
            *(ushort4*)&xls[sr][sc + 4]  = u1;
            *(ushort4*)&xls[sr][sc + 8]  = u2;
            *(ushort4*)&xls[sr][sc + 12] = u3;
        }
    }
    __syncthreads();

    int wave = t >> 6, lane = t & 63, quad = lane >> 4, l15 = lane & 15;
    f32x4 acc[4][4];   // [rowgroup][nt] — all indices compile-time constant
    #pragma unroll
    for (int rg = 0; rg < 4; rg++)
        #pragma unroll
        for (int nt = 0; nt < 4; nt++) acc[rg][nt] = (f32x4){0.f, 0.f, 0.f, 0.f};

    #pragma unroll
    for (int ks = 0; ks < 8; ks++) {
        short8 bfr[4];
        #pragma unroll
        for (int nt = 0; nt < 4; nt++)
            bfr[nt] = *(const short8*)(wswz +
                ((long)((ks * 16 + wave * 4 + nt) * 64 + lane)) * 8);
        #pragma unroll
        for (int rg = 0; rg < 4; rg++) {
            short8 af = *(const short8*)&xls[rg * 16 + l15][ks * 32 + quad * 8];
            #pragma unroll
            for (int nt = 0; nt < 4; nt++)
                acc[rg][nt] = __builtin_amdgcn_mfma_f32_16x16x32_bf16(
                    af, bfr[nt], acc[rg][nt], 0, 0, 0);
        }
    }

    // hswz store (B-frag order for k_attn), per rowgroup
    int q0 = (quad & 1) * 4;
    #pragma unroll
    for (int rg = 0; rg < 4; rg++) {
        int row0g = row0 + rg * 16;
        int qd = ((row0g & 31) + quad * 4) >> 3;
        long bj32 = row0g >> 5;
        #pragma unroll
        for (int nt = 0; nt < 4; nt++) {
            int dg = wave * 4 + nt;
            long idx8 = (bj32 * 16 + dg) * 64 + qd * 16 + l15;
            ushort4 o = {f2bf(acc[rg][nt][0]), f2bf(acc[rg][nt][1]),
                         f2bf(acc[rg][nt][2]), f2bf(acc[rg][nt][3])};
            *(ushort4*)&hswz[idx8 * 8 + q0] = o;
        }
    }

    // fused scores -> row factor + exp pairs, pre-scaled by log2(e)
    float as_[4], ad_[4];
    #pragma unroll
    for (int nt = 0; nt < 4; nt++) {
        int d = nt * 16 + l15;
        as_[nt] = a[d * NH_ + wave];
        ad_[nt] = a[(64 + d) * NH_ + wave];
    }
    #pragma unroll
    for (int rg = 0; rg < 4; rg++) {
        #pragma unroll
        for (int r = 0; r < 4; r++) {
            float ps = acc[rg][0][r] * as_[0] + acc[rg][1][r] * as_[1]
                     + acc[rg][2][r] * as_[2] + acc[rg][3][r] * as_[3];
            float pd = acc[rg][0][r] * ad_[0] + acc[rg][1][r] * ad_[1]
                     + acc[rg][2][r] * ad_[2] + acc[rg][3][r] * ad_[3];
            #pragma unroll
            for (int m = 1; m < 16; m <<= 1) {
                ps += __shfl_xor(ps, m);
                pd += __shfl_xor(pd, m);
            }
            if (l15 == 0) {
                int row = n0 + rg * 16 + quad * 4 + r;
                float s1 = ps * L2E, s2 = pd * L2E;
                esr[((long)b * NH_ + wave) * N_ + row] = __builtin_exp2f(-0.8f * s1);
                edst[((long)b * NH_ + wave) * N_ + row] =
                    make_float2(__builtin_exp2f(s2), __builtin_exp2f(0.2f * s2));
            }
        }
    }
}

// ---------------------------------------------------------------------------
// Kernel C: masked softmax + MFMA aggregate — 2-STRIP WAVES + HEAD-GROUPED
// BLOCKS + JH SPLIT (the untested cell of the design space).
// L1-return-BW model: delivered B-frag bytes = strips x 32jc x 4KB; only
// more rows per B-read cuts it. 2-strip waves (R1/R5 body: 4 bf loads
// feed 10 MFMAs) halve per-CU delivery 2MB -> 1MB vs R9-11, while head
// grouping keeps the per-jc live set L1-resident (8KB) and the jh split
// keeps 16 waves/CU at 2 blocks/CU.
// grid = 512 blocks (16b x 4h x 8 rowgroups of 128, XCD-swizzled: 2 b/XCD
// L2-resident) x 512 thr = 8 waves = 4 strip-pairs (sp) x 2 jh.
// LDS: esb 8KB + accb 40KB + mtab = 49KB -> 2 blocks/CU. VGPR ~60 at
// (512,4) -> 4 waves/SIMD (NEVER min>=8: R2/R3 collapse; macros also
// collapse VGPR: R7 — keep fat straight-line body).
// Weight pipeline: w = fmax(D1_j, r_i*D2_j) (E1 cancels in softmax),
// cvt_pk pack, 16-entry LDS nibble mask table, transposed-pb coalesced.
// ---------------------------------------------------------------------------
__global__ __launch_bounds__(512, 4) void k_attn(
    const unsigned int* __restrict__ pb, const unsigned short* __restrict__ hswz,
    const float* __restrict__ esr, const float2* __restrict__ edst,
    float* __restrict__ out)
{
    __shared__ float2 esb[1024];               // 8 KB: edst slice for (b, hh)
    __shared__ uint2 mtab[16];
    __shared__ float accb[4][2][64][20];       // 40 KB [sp][strip][lane][16+4]

    int t = threadIdx.x;
    int bid = blockIdx.x;
    int swz = (bid & 7) * 64 + (bid >> 3);     // bijective (512 % 8 == 0)
    int b  = swz >> 5;                          // 2 b per XCD -> L2-resident
    int hh = (swz >> 3) & 3;
    int rg = swz & 7;
    int row0 = rg * 128;

    int wave = t >> 6, lane = t & 63, quad = lane >> 4, l15 = lane & 15;
    int sp = wave & 3, jh = wave >> 2;

    esb[t]       = edst[((long)(b * NH_ + hh)) * N_ + t];
    esb[t + 512] = edst[((long)(b * NH_ + hh)) * N_ + t + 512];
    if (t < 16) {
        int k = t;
        unsigned int w0 = ((k & 1) ? 0xffffu : 0u) | ((k & 2) ? 0xffff0000u : 0u);
        unsigned int w1 = ((k & 4) ? 0xffffu : 0u) | ((k & 8) ? 0xffff0000u : 0u);
        mtab[k] = make_uint2(w0, w1);
    }
    __syncthreads();

    int ir0 = row0 + sp * 32 + l15;            // strip0 row; strip1 = +16
    float r0 = esr[((long)(b * NH_ + hh)) * N_ + ir0];
    float r1 = esr[((long)(b * NH_ + hh)) * N_ + ir0 + 16];
    // transposed pb: word W at pb[W*16384 + b*1024 + row] (coalesced)
    const unsigned int* pbw = pb + ((long)b << 10) + ir0;

    f32x4 acc0[4], acc1[4], dn0, dn1;
    #pragma unroll
    for (int i = 0; i < 4; i++) {
        acc0[i] = (f32x4){0.f, 0.f, 0.f, 0.f};
        acc1[i] = (f32x4){0.f, 0.f, 0.f, 0.f};
    }
    dn0 = (f32x4){0.f, 0.f, 0.f, 0.f};
    dn1 = (f32x4){0.f, 0.f, 0.f, 0.f};
    short8 ones;
    #pragma unroll
    for (int i = 0; i < 8; i++) ones[i] = (short)0x3F80;   // bf16 1.0

    int shq = quad * 8;

    #pragma unroll 4
    for (int jc = 0; jc < 16; jc++) {
        int w = jh * 16 + jc;
        unsigned int m0 = (pbw[((long)w << 14)] >> shq) & 0xffu;        // strip0
        unsigned int m1 = (pbw[((long)w << 14) + 16] >> shq) & 0xffu;   // strip1
        const f32x4* ej = (const f32x4*)&esb[w * 32 + quad * 8];

        union { unsigned int u[4]; short8 s; } p0, p1;
        #pragma unroll
        for (int qp = 0; qp < 4; qp++) {
            f32x4 d = ej[qp];   // {D1_j, D2_j, D1_j', D2_j'} for j=2qp, 2qp+1
            p0.u[qp] = cvt_pk_bf16(fmaxf(d[0], r0 * d[1]), fmaxf(d[2], r0 * d[3]));
            p1.u[qp] = cvt_pk_bf16(fmaxf(d[0], r1 * d[1]), fmaxf(d[2], r1 * d[3]));
        }
        uint2 ma0 = mtab[m0 & 15u], mb0 = mtab[m0 >> 4];
        uint2 ma1 = mtab[m1 & 15u], mb1 = mtab[m1 >> 4];
        p0.u[0] &= ma0.x; p0.u[1] &= ma0.y; p0.u[2] &= mb0.x; p0.u[3] &= mb0.y;
        p1.u[0] &= ma1.x; p1.u[1] &= ma1.y; p1.u[2] &= mb1.x; p1.u[3] &= mb1.y;

        long s8 = ((long)(b * 32 + w)) * 1024;
        #pragma unroll
        for (int idt = 0; idt < 4; idt++) {
            short8 bf = *(const short8*)(hswz + (s8 + (hh * 4 + idt) * 64 + lane) * 8);
            acc0[idt] = __builtin_amdgcn_mfma_f32_16x16x32_bf16(p0.s, bf, acc0[idt], 0, 0, 0);
            acc1[idt] = __builtin_amdgcn_mfma_f32_16x16x32_bf16(p1.s, bf, acc1[idt], 0, 0, 0);
        }
        dn0 = __builtin_amdgcn_mfma_f32_16x16x32_bf16(p0.s, ones, dn0, 0, 0, 0);
        dn1 = __builtin_amdgcn_mfma_f32_16x16x32_bf16(p1.s, ones, dn1, 0, 0, 0);
    }

    // ---- jh combine via LDS, then normalize + store ----
    if (jh == 1) {
        #pragma unroll
        for (int idt = 0; idt < 4; idt++) {
            *(f32x4*)&accb[sp][0][lane][idt * 4] = acc0[idt];
            *(f32x4*)&accb[sp][1][lane][idt * 4] = acc1[idt];
        }
        *(f32x4*)&accb[sp][0][lane][16] = dn0;
        *(f32x4*)&accb[sp][1][lane][16] = dn1;
    }
    __syncthreads();

    if (jh == 0) {
        f32x4 od0 = *(const f32x4*)&accb[sp][0][lane][16];
        f32x4 od1 = *(const f32x4*)&accb[sp][1][lane][16];
        float inv0[4], inv1[4];
        #pragma unroll
        for (int r = 0; r < 4; r++) {
            inv0[r] = 1.0f / (dn0[r] + od0[r]);
            inv1[r] = 1.0f / (dn1[r] + od1[r]);
        }
        #pragma unroll
        for (int idt = 0; idt < 4; idt++) {
            f32x4 o0 = *(const f32x4*)&accb[sp][0][lane][idt * 4];
            f32x4 o1 = *(const f32x4*)&accb[sp][1][lane][idt * 4];
            int col = hh * 64 + idt * 16 + l15;
            #pragma unroll
            for (int r = 0; r < 4; r++) {
                long row_g = (long)b * N_ + row0 + sp * 32 + quad * 4 + r;
                out[row_g * HD_ + col] = (acc0[idt][r] + o0[r]) * inv0[r];
                out[(row_g + 16) * HD_ + col] = (acc1[idt][r] + o1[r]) * inv1[r];
            }
        }
    }
}

extern "C" void kernel_launch(void* const* d_in, const int* in_sizes, int n_in,
                              void* d_out, int out_size, void* d_ws, size_t ws_size,
                              hipStream_t stream) {
    const float* x   = (const float*)d_in[0];
    const int*   adj = (const int*)d_in[1];
    const float* W   = (const float*)d_in[2];
    const float* a   = (const float*)d_in[3];
    float* out = (float*)d_out;

    unsigned int* pb      = (unsigned int*)d_ws;                       // 2 MB
    unsigned short* hswz  = (unsigned short*)(pb + 524288);            // 8 MB
    unsigned short* wswz  = hswz + (long)B_ * N_ * HD_;                // 128 KB
    float* esr   = (float*)(wswz + INF_ * HD_);                        // 256 KB
    float2* edst = (float2*)(esr + (long)B_ * NH_ * N_);               // 512 KB

    k_prep<<<2080, 256, 0, stream>>>(adj, W, pb, wswz);
    k_gemm_h<<<256, 256, 0, stream>>>(x, a, wswz, hswz, esr, edst);
    k_attn<<<512, 512, 0, stream>>>(pb, hswz, esr, edst, out);
}

// Round 13
// 143.419 us; speedup vs baseline: 1.0495x; 1.0296x over previous
//
#include <hip/hip_runtime.h>
#include <hip/hip_bf16.h>

#define B_   16
#define N_   1024
#define INF_ 256
#define NH_  4
#define HD_  256
#define L2E  1.4426950408889634f

typedef __attribute__((ext_vector_type(8))) short short8;
typedef __attribute__((ext_vector_type(4))) float f32x4;

__device__ __forceinline__ float bf2f(unsigned short u) {
    union { unsigned int i; float f; } v; v.i = ((unsigned int)u) << 16; return v.f;
}
__device__ __forceinline__ unsigned short f2bf(float f) {
    union { float f; unsigned int i; } v; v.f = f;
    unsigned int x = v.i;
    return (unsigned short)((x + 0x7fffu + ((x >> 16) & 1u)) >> 16);
}
// pack 2 f32 -> 2 bf16 in one op (low16 = lo, high16 = hi); no builtin on gfx950
__device__ __forceinline__ unsigned int cvt_pk_bf16(float lo, float hi) {
    unsigned int r;
    asm("v_cvt_pk_bf16_f32 %0, %1, %2" : "=v"(r) : "v"(lo), "v"(hi));
    return r;
}

// ---------------------------------------------------------------------------
// Kernel PREP (fused):
//  blocks [0,2048): pack adj -> TRANSPOSED bitmask pb[word][grow] (uint32,
//    bit p of word w = adj[row][w*32+p]); k_attn mask loads are coalesced.
//  blocks [2048,2080): W fp32 -> wswz bf16 in MFMA B-frag order.
// ~11us floor (67MB adj read, HBM-bound) — at roofline, unchanged.
// ---------------------------------------------------------------------------
__global__ __launch_bounds__(256) void k_prep(const int* __restrict__ adj,
                                              const float* __restrict__ W,
                                              unsigned int* __restrict__ pb,
                                              unsigned short* __restrict__ wswz)
{
    int bx = blockIdx.x, t = threadIdx.x;
    if (bx < 2048) {
        int wave = t >> 6, lane = t & 63;
        int row = bx * 8 + wave * 2 + (lane >> 5);   // [0, 16384)
        int w   = lane & 31;
        const int4* ar = (const int4*)(adj + ((long)row << 10) + w * 32);
        unsigned int u = 0;
        #pragma unroll
        for (int k = 0; k < 8; k++) {
            int4 a = ar[k];
            u |= ((unsigned)a.x) << (4 * k);
            u |= ((unsigned)a.y) << (4 * k + 1);
            u |= ((unsigned)a.z) << (4 * k + 2);
            u |= ((unsigned)a.w) << (4 * k + 3);
        }
        pb[((long)w << 14) + row] = u;               // TRANSPOSED: [word][grow]
    } else {
        int slot = (bx - 2048) * 256 + t;
        int kstep = slot >> 10;
        int nt    = (slot >> 6) & 15;
        int lane  = slot & 63;
        int k0 = kstep * 32 + (lane >> 4) * 8;
        int n  = nt * 16 + (lane & 15);
        ushort4 o0, o1;
        o0.x = f2bf(W[(k0 + 0) * HD_ + n]);
        o0.y = f2bf(W[(k0 + 1) * HD_ + n]);
        o0.z = f2bf(W[(k0 + 2) * HD_ + n]);
        o0.w = f2bf(W[(k0 + 3) * HD_ + n]);
        o1.x = f2bf(W[(k0 + 4) * HD_ + n]);
        o1.y = f2bf(W[(k0 + 5) * HD_ + n]);
        o1.z = f2bf(W[(k0 + 6) * HD_ + n]);
        o1.w = f2bf(W[(k0 + 7) * HD_ + n]);
        *(ushort4*)&wswz[(long)slot * 8]     = o0;
        *(ushort4*)&wswz[(long)slot * 8 + 4] = o1;
    }
}

// ---------------------------------------------------------------------------
// Kernel A: h = x @ W via MFMA — 64-ROW BLOCKS for 4x B-frag reuse.
// grid 256 x 256 thr (4 waves, one head each), 64 rows; per ks the 4
// B-frags load ONCE into regs, reused across 4 row-groups.
// Emits hswz (B-frag order bf16) + per-row factors:
//   esr[(b,h,i)]  = exp2(-0.8*ss)   (E1 cancels in softmax -> dropped)
//   edst[(b,h,j)] = {exp2(sd), exp2(0.2*sd)}
// ---------------------------------------------------------------------------
__global__ __launch_bounds__(256, 4) void k_gemm_h(
    const float* __restrict__ x, const float* __restrict__ a,
    const unsigned short* __restrict__ wswz,
    unsigned short* __restrict__ hswz,
    float* __restrict__ esr, float2* __restrict__ edst)
{
    __shared__ unsigned short xls[64][264];
    int t = threadIdx.x;
    int blk = blockIdx.x;            // 256 blocks
    int row0 = blk * 64;
    int b  = blk >> 4;
    int n0 = row0 & 1023;

    {
        int sr0 = t >> 4, sc = (t & 15) * 16;
        #pragma unroll
        for (int rr = 0; rr < 4; rr++) {
            int sr = sr0 + rr * 16;
            const float* xp = x + (long)(row0 + sr) * INF_ + sc;
            float4 v0 = ((const float4*)xp)[0];
            float4 v1 = ((const float4*)xp)[1];
            float4 v2 = ((const float4*)xp)[2];
            float4 v3 = ((const float4*)xp)[3];
            ushort4 u0 = {f2bf(v0.x), f2bf(v0.y), f2bf(v0.z), f2bf(v0.w)};
            ushort4 u1 = {f2bf(v1.x), f2bf(v1.y), f2bf(v1.z), f2bf(v1.w)};
            ushort4 u2 = {f2bf(v2.x), f2bf(v2.y), f2bf(v2.z), f2bf(v2.w)};
            ushort4 u3 = {f2bf(v3.x), f2bf(v3.y), f2bf(v3.z), f2bf(v3.w)};
            *(ushort4*)&xls[sr][sc]      = u0;
            *(ushort4*)&xls[sr][sc + 4]  = u1;
            *(ushort4*)&xls[sr][sc + 8]  = u2;
            *(ushort4*)&xls[sr][sc + 12] = u3;
        }
    }
    __syncthreads();

    int wave = t >> 6, lane = t & 63, quad = lane >> 4, l15 = lane & 15;
    f32x4 acc[4][4];   // [rowgroup][nt] — all indices compile-time constant
    #pragma unroll
    for (int rg = 0; rg < 4; rg++)
        #pragma unroll
        for (int nt = 0; nt < 4; nt++) acc[rg][nt] = (f32x4){0.f, 0.f, 0.f, 0.f};

    #pragma unroll
    for (int ks = 0; ks < 8; ks++) {
        short8 bfr[4];
        #pragma unroll
        for (int nt = 0; nt < 4; nt++)
            bfr[nt] = *(const short8*)(wswz +
                ((long)((ks * 16 + wave * 4 + nt) * 64 + lane)) * 8);
        #pragma unroll
        for (int rg = 0; rg < 4; rg++) {
            short8 af = *(const short8*)&xls[rg * 16 + l15][ks * 32 + quad * 8];
            #pragma unroll
            for (int nt = 0; nt < 4; nt++)
                acc[rg][nt] = __builtin_amdgcn_mfma_f32_16x16x32_bf16(
                    af, bfr[nt], acc[rg][nt], 0, 0, 0);
        }
    }

    // hswz store (B-frag order for k_attn), per rowgroup
    int q0 = (quad & 1) * 4;
    #pragma unroll
    for (int rg = 0; rg < 4; rg++) {
        int row0g = row0 + rg * 16;
        int qd = ((row0g & 31) + quad * 4) >> 3;
        long bj32 = row0g >> 5;
        #pragma unroll
        for (int nt = 0; nt < 4; nt++) {
            int dg = wave * 4 + nt;
            long idx8 = (bj32 * 16 + dg) * 64 + qd * 16 + l15;
            ushort4 o = {f2bf(acc[rg][nt][0]), f2bf(acc[rg][nt][1]),
                         f2bf(acc[rg][nt][2]), f2bf(acc[rg][nt][3])};
            *(ushort4*)&hswz[idx8 * 8 + q0] = o;
        }
    }

    // fused scores -> row factor + exp pairs, pre-scaled by log2(e)
    float as_[4], ad_[4];
    #pragma unroll
    for (int nt = 0; nt < 4; nt++) {
        int d = nt * 16 + l15;
        as_[nt] = a[d * NH_ + wave];
        ad_[nt] = a[(64 + d) * NH_ + wave];
    }
    #pragma unroll
    for (int rg = 0; rg < 4; rg++) {
        #pragma unroll
        for (int r = 0; r < 4; r++) {
            float ps = acc[rg][0][r] * as_[0] + acc[rg][1][r] * as_[1]
                     + acc[rg][2][r] * as_[2] + acc[rg][3][r] * as_[3];
            float pd = acc[rg][0][r] * ad_[0] + acc[rg][1][r] * ad_[1]
                     + acc[rg][2][r] * ad_[2] + acc[rg][3][r] * ad_[3];
            #pragma unroll
            for (int m = 1; m < 16; m <<= 1) {
                ps += __shfl_xor(ps, m);
                pd += __shfl_xor(pd, m);
            }
            if (l15 == 0) {
                int row = n0 + rg * 16 + quad * 4 + r;
                float s1 = ps * L2E, s2 = pd * L2E;
                esr[((long)b * NH_ + wave) * N_ + row] = __builtin_exp2f(-0.8f * s1);
                edst[((long)b * NH_ + wave) * N_ + row] =
                    make_float2(__builtin_exp2f(s2), __builtin_exp2f(0.2f * s2));
            }
        }
    }
}

// ---------------------------------------------------------------------------
// Kernel C: masked softmax + MFMA aggregate — R12 structure (2-strip waves
// + head-grouped blocks + jh split; best measured) + SOURCE-LEVEL MLP:
//  (1) pb mask preload: all 32 mask bytes loaded in one burst before the
//      loop, packed into 8 VGPRs (static-indexed under full unroll) —
//      removes the pb L2 latency from every jc chain.
//  (2) hswz register double-buffer bfA/bfB at prefetch distance 1,
//      written as a fat inline jc+=2 fully-unrolled loop (no macros —
//      R7 VGPR collapse; no runtime buffer index — scratch rule) —
//      hswz loads leave the consume chain.
// Rationale: compiler minimizes VGPR (~56-60) leaving no MLP headroom;
// forcing ~110 VGPR of in-flight state stays under the 128 cap ->
// still 2 blocks/CU = 4 waves/SIMD.
// grid = 512 blocks (16b x 4h x 8 rowgroups of 128, XCD-swizzled) x 512
// thr = 8 waves = 4 strip-pairs (sp) x 2 jh. LDS 49KB. (512,4) ONLY.
// ---------------------------------------------------------------------------
__global__ __launch_bounds__(512, 4) void k_attn(
    const unsigned int* __restrict__ pb, const unsigned short* __restrict__ hswz,
    const float* __restrict__ esr, const float2* __restrict__ edst,
    float* __restrict__ out)
{
    __shared__ float2 esb[1024];               // 8 KB: edst slice for (b, hh)
    __shared__ uint2 mtab[16];
    __shared__ float accb[4][2][64][20];       // 40 KB [sp][strip][lane][16+4]

    int t = threadIdx.x;
    int bid = blockIdx.x;
    int swz = (bid & 7) * 64 + (bid >> 3);     // bijective (512 % 8 == 0)
    int b  = swz >> 5;                          // 2 b per XCD -> L2-resident
    int hh = (swz >> 3) & 3;
    int rg = swz & 7;
    int row0 = rg * 128;

    int wave = t >> 6, lane = t & 63, quad = lane >> 4, l15 = lane & 15;
    int sp = wave & 3, jh = wave >> 2;

    esb[t]       = edst[((long)(b * NH_ + hh)) * N_ + t];
    esb[t + 512] = edst[((long)(b * NH_ + hh)) * N_ + t + 512];
    if (t < 16) {
        int k = t;
        unsigned int w0 = ((k & 1) ? 0xffffu : 0u) | ((k & 2) ? 0xffff0000u : 0u);
        unsigned int w1 = ((k & 4) ? 0xffffu : 0u) | ((k & 8) ? 0xffff0000u : 0u);
        mtab[k] = make_uint2(w0, w1);
    }
    __syncthreads();

    int ir0 = row0 + sp * 32 + l15;            // strip0 row; strip1 = +16
    float r0 = esr[((long)(b * NH_ + hh)) * N_ + ir0];
    float r1 = esr[((long)(b * NH_ + hh)) * N_ + ir0 + 16];
    const unsigned int* pbw = pb + ((long)b << 10) + ir0;
    int shq = quad * 8;

    // ---- (1) mask preload: 32 coalesced loads -> 8 packed VGPRs ----
    unsigned int mpk0[4], mpk1[4];
    #pragma unroll
    for (int g = 0; g < 4; g++) {
        unsigned int a0 = 0, a1 = 0;
        #pragma unroll
        for (int k = 0; k < 4; k++) {
            int w = jh * 16 + g * 4 + k;
            a0 |= ((pbw[(long)w << 14] >> shq) & 0xffu) << (8 * k);
            a1 |= ((pbw[((long)w << 14) + 16] >> shq) & 0xffu) << (8 * k);
        }
        mpk0[g] = a0; mpk1[g] = a1;
    }

    f32x4 acc0[4], acc1[4], dn0, dn1;
    #pragma unroll
    for (int i = 0; i < 4; i++) {
        acc0[i] = (f32x4){0.f, 0.f, 0.f, 0.f};
        acc1[i] = (f32x4){0.f, 0.f, 0.f, 0.f};
    }
    dn0 = (f32x4){0.f, 0.f, 0.f, 0.f};
    dn1 = (f32x4){0.f, 0.f, 0.f, 0.f};
    short8 ones;
    #pragma unroll
    for (int i = 0; i < 8; i++) ones[i] = (short)0x3F80;   // bf16 1.0

    // ---- (2) hswz register double-buffer, prefetch distance 1 ----
    // frag (local w, idt) at hbase + w*8192 + idt*512 (ushort units)
    const unsigned short* hbase = hswz +
        (((long)(b * 32 + jh * 16)) * 1024 + (hh * 4) * 64 + lane) * 8;

    short8 bfA[4], bfB[4];
    #pragma unroll
    for (int idt = 0; idt < 4; idt++)
        bfA[idt] = *(const short8*)(hbase + idt * 512);

    #pragma unroll
    for (int jc = 0; jc < 16; jc += 2) {
        // prefetch jc+1 into bfB (off-chain)
        #pragma unroll
        for (int idt = 0; idt < 4; idt++)
            bfB[idt] = *(const short8*)(hbase + (long)(jc + 1) * 8192 + idt * 512);

        // weights for jc
        {
            int w = jh * 16 + jc;
            const f32x4* ej = (const f32x4*)&esb[w * 32 + quad * 8];
            union { unsigned int u[4]; short8 s; } p0, p1;
            #pragma unroll
            for (int qp = 0; qp < 4; qp++) {
                f32x4 d = ej[qp];   // {D1_j, D2_j, D1_j', D2_j'}
                p0.u[qp] = cvt_pk_bf16(fmaxf(d[0], r0 * d[1]), fmaxf(d[2], r0 * d[3]));
                p1.u[qp] = cvt_pk_bf16(fmaxf(d[0], r1 * d[1]), fmaxf(d[2], r1 * d[3]));
            }
            unsigned int m0 = (mpk0[jc >> 2] >> ((jc & 3) * 8)) & 0xffu;
            unsigned int m1 = (mpk1[jc >> 2] >> ((jc & 3) * 8)) & 0xffu;
            uint2 ma0 = mtab[m0 & 15u], mb0 = mtab[m0 >> 4];
            uint2 ma1 = mtab[m1 & 15u], mb1 = mtab[m1 >> 4];
            p0.u[0] &= ma0.x; p0.u[1] &= ma0.y; p0.u[2] &= mb0.x; p0.u[3] &= mb0.y;
            p1.u[0] &= ma1.x; p1.u[1] &= ma1.y; p1.u[2] &= mb1.x; p1.u[3] &= mb1.y;

            #pragma unroll
            for (int idt = 0; idt < 4; idt++) {
                acc0[idt] = __builtin_amdgcn_mfma_f32_16x16x32_bf16(p0.s, bfA[idt], acc0[idt], 0, 0, 0);
                acc1[idt] = __builtin_amdgcn_mfma_f32_16x16x32_bf16(p1.s, bfA[idt], acc1[idt], 0, 0, 0);
            }
            dn0 = __builtin_amdgcn_mfma_f32_16x16x32_bf16(p0.s, ones, dn0, 0, 0, 0);
            dn1 = __builtin_amdgcn_mfma_f32_16x16x32_bf16(p1.s, ones, dn1, 0, 0, 0);
        }

        // prefetch jc+2 into bfA (last iter: re-read jc+1, in-bounds, unused cost)
        {
            int wn = (jc + 2 < 16) ? jc + 2 : jc + 1;
            #pragma unroll
            for (int idt = 0; idt < 4; idt++)
                bfA[idt] = *(const short8*)(hbase + (long)wn * 8192 + idt * 512);
        }

        // weights for jc+1
        {
            int jd = jc + 1;
            int w = jh * 16 + jd;
            const f32x4* ej = (const f32x4*)&esb[w * 32 + quad * 8];
            union { unsigned int u[4]; short8 s; } p0, p1;
            #pragma unroll
            for (int qp = 0; qp < 4; qp++) {
                f32x4 d = ej[qp];
                p0.u[qp] = cvt_pk_bf16(fmaxf(d[0], r0 * d[1]), fmaxf(d[2], r0 * d[3]));
                p1.u[qp] = cvt_pk_bf16(fmaxf(d[0], r1 * d[1]), fmaxf(d[2], r1 * d[3]));
            }
            unsigned int m0 = (mpk0[jd >> 2] >> ((jd & 3) * 8)) & 0xffu;
            unsigned int m1 = (mpk1[jd >> 2] >> ((jd & 3) * 8)) & 0xffu;
            uint2 ma0 = mtab[m0 & 15u], mb0 = mtab[m0 >> 4];
            uint2 ma1 = mtab[m1 & 15u], mb1 = mtab[m1 >> 4];
            p0.u[0] &= ma0.x; p0.u[1] &= ma0.y; p0.u[2] &= mb0.x; p0.u[3] &= mb0.y;
            p1.u[0] &= ma1.x; p1.u[1] &= ma1.y; p1.u[2] &= mb1.x; p1.u[3] &= mb1.y;

            #pragma unroll
            for (int idt = 0; idt < 4; idt++) {
                acc0[idt] = __builtin_amdgcn_mfma_f32_16x16x32_bf16(p0.s, bfB[idt], acc0[idt], 0, 0, 0);
                acc1[idt] = __builtin_amdgcn_mfma_f32_16x16x32_bf16(p1.s, bfB[idt], acc1[idt], 0, 0, 0);
            }
            dn0 = __builtin_amdgcn_mfma_f32_16x16x32_bf16(p0.s, ones, dn0, 0, 0, 0);
            dn1 = __builtin_amdgcn_mfma_f32_16x16x32_bf16(p1.s, ones, dn1, 0, 0, 0);
        }
    }

    // ---- jh combine via LDS, then normalize + store ----
    if (jh == 1) {
        #pragma unroll
        for (int idt = 0; idt < 4; idt++) {
            *(f32x4*)&accb[sp][0][lane][idt * 4] = acc0[idt];
            *(f32x4*)&accb[sp][1][lane][idt * 4] = acc1[idt];
        }
        *(f32x4*)&accb[sp][0][lane][16] = dn0;
        *(f32x4*)&accb[sp][1][lane][16] = dn1;
    }
    __syncthreads();

    if (jh == 0) {
        f32x4 od0 = *(const f32x4*)&accb[sp][0][lane][16];
        f32x4 od1 = *(const f32x4*)&accb[sp][1][lane][16];
        float inv0[4], inv1[4];
        #pragma unroll
        for (int r = 0; r < 4; r++) {
            inv0[r] = 1.0f / (dn0[r] + od0[r]);
            inv1[r] = 1.0f / (dn1[r] + od1[r]);
        }
        #pragma unroll
        for (int idt = 0; idt < 4; idt++) {
            f32x4 o0 = *(const f32x4*)&accb[sp][0][lane][idt * 4];
            f32x4 o1 = *(const f32x4*)&accb[sp][1][lane][idt * 4];
            int col = hh * 64 + idt * 16 + l15;
            #pragma unroll
            for (int r = 0; r < 4; r++) {
                long row_g = (long)b * N_ + row0 + sp * 32 + quad * 4 + r;
                out[row_g * HD_ + col] = (acc0[idt][r] + o0[r]) * inv0[r];
                out[(row_g + 16) * HD_ + col] = (acc1[idt][r] + o1[r]) * inv1[r];
            }
        }
    }
}

extern "C" void kernel_launch(void* const* d_in, const int* in_sizes, int n_in,
                              void* d_out, int out_size, void* d_ws, size_t ws_size,
                              hipStream_t stream) {
    const float* x   = (const float*)d_in[0];
    const int*   adj = (const int*)d_in[1];
    const float* W   = (const float*)d_in[2];
    const float* a   = (const float*)d_in[3];
    float* out = (float*)d_out;

    unsigned int* pb      = (unsigned int*)d_ws;                       // 2 MB
    unsigned short* hswz  = (unsigned short*)(pb + 524288);            // 8 MB
    unsigned short* wswz  = hswz + (long)B_ * N_ * HD_;                // 128 KB
    float* esr   = (float*)(wswz + INF_ * HD_);                        // 256 KB
    float2* edst = (float2*)(esr + (long)B_ * NH_ * N_);               // 512 KB

    k_prep<<<2080, 256, 0, stream>>>(adj, W, pb, wswz);
    k_gemm_h<<<256, 256, 0, stream>>>(x, a, wswz, hswz, esr, edst);
    k_attn<<<512, 512, 0, stream>>>(pb, hswz, esr, edst, out);
}

// Round 14
// 140.698 us; speedup vs baseline: 1.0698x; 1.0193x over previous
//
#include <hip/hip_runtime.h>
#include <hip/hip_bf16.h>

#define B_   16
#define N_   1024
#define INF_ 256
#define NH_  4
#define HD_  256
#define L2E  1.4426950408889634f

typedef __attribute__((ext_vector_type(8))) short short8;
typedef __attribute__((ext_vector_type(4))) float f32x4;

__device__ __forceinline__ float bf2f(unsigned short u) {
    union { unsigned int i; float f; } v; v.i = ((unsigned int)u) << 16; return v.f;
}
__device__ __forceinline__ unsigned short f2bf(float f) {
    union { float f; unsigned int i; } v; v.f = f;
    unsigned int x = v.i;
    return (unsigned short)((x + 0x7fffu + ((x >> 16) & 1u)) >> 16);
}
// pack 2 f32 -> 2 bf16 in one op (low16 = lo, high16 = hi); no builtin on gfx950
__device__ __forceinline__ unsigned int cvt_pk_bf16(float lo, float hi) {
    unsigned int r;
    asm("v_cvt_pk_bf16_f32 %0, %1, %2" : "=v"(r) : "v"(lo), "v"(hi));
    return r;
}

// ---------------------------------------------------------------------------
// Kernel PREP (fused):
//  blocks [0,2048): pack adj -> TRANSPOSED bitmask pb[word][grow] (uint32,
//    bit p of word w = adj[row][w*32+p]); k_attn mask loads are coalesced.
//  blocks [2048,2080): W fp32 -> wswz bf16 in MFMA B-frag order.
// ~11us floor (67MB adj read, HBM-bound) — at roofline, unchanged.
// ---------------------------------------------------------------------------
__global__ __launch_bounds__(256) void k_prep(const int* __restrict__ adj,
                                              const float* __restrict__ W,
                                              unsigned int* __restrict__ pb,
                                              unsigned short* __restrict__ wswz)
{
    int bx = blockIdx.x, t = threadIdx.x;
    if (bx < 2048) {
        int wave = t >> 6, lane = t & 63;
        int row = bx * 8 + wave * 2 + (lane >> 5);   // [0, 16384)
        int w   = lane & 31;
        const int4* ar = (const int4*)(adj + ((long)row << 10) + w * 32);
        unsigned int u = 0;
        #pragma unroll
        for (int k = 0; k < 8; k++) {
            int4 a = ar[k];
            u |= ((unsigned)a.x) << (4 * k);
            u |= ((unsigned)a.y) << (4 * k + 1);
            u |= ((unsigned)a.z) << (4 * k + 2);
            u |= ((unsigned)a.w) << (4 * k + 3);
        }
        pb[((long)w << 14) + row] = u;               // TRANSPOSED: [word][grow]
    } else {
        int slot = (bx - 2048) * 256 + t;
        int kstep = slot >> 10;
        int nt    = (slot >> 6) & 15;
        int lane  = slot & 63;
        int k0 = kstep * 32 + (lane >> 4) * 8;
        int n  = nt * 16 + (lane & 15);
        ushort4 o0, o1;
        o0.x = f2bf(W[(k0 + 0) * HD_ + n]);
        o0.y = f2bf(W[(k0 + 1) * HD_ + n]);
        o0.z = f2bf(W[(k0 + 2) * HD_ + n]);
        o0.w = f2bf(W[(k0 + 3) * HD_ + n]);
        o1.x = f2bf(W[(k0 + 4) * HD_ + n]);
        o1.y = f2bf(W[(k0 + 5) * HD_ + n]);
        o1.z = f2bf(W[(k0 + 6) * HD_ + n]);
        o1.w = f2bf(W[(k0 + 7) * HD_ + n]);
        *(ushort4*)&wswz[(long)slot * 8]     = o0;
        *(ushort4*)&wswz[(long)slot * 8 + 4] = o1;
    }
}

// ---------------------------------------------------------------------------
// Kernel A: h = x @ W via MFMA — 64-ROW BLOCKS for 4x B-frag reuse.
// grid 256 x 256 thr (4 waves, one head each), 64 rows; per ks the 4
// B-frags load ONCE into regs, reused across 4 row-groups.
// Emits hswz (B-frag order bf16) + per-row factors:
//   esr[(b,h,i)]  = exp2(-0.8*ss)   (E1 cancels in softmax -> dropped)
//   edst[(b,h,j)] = {exp2(sd), exp2(0.2*sd)}
// ---------------------------------------------------------------------------
__global__ __launch_bounds__(256, 4) void k_gemm_h(
    const float* __restrict__ x, const float* __restrict__ a,
    const unsigned short* __restrict__ wswz,
    unsigned short* __restrict__ hswz,
    float* __restrict__ esr, float2* __restrict__ edst)
{
    __shared__ unsigned short xls[64][264];
    int t = threadIdx.x;
    int blk = blockIdx.x;            // 256 blocks
    int row0 = blk * 64;
    int b  = blk >> 4;
    int n0 = row0 & 1023;

    {
        int sr0 = t >> 4, sc = (t & 15) * 16;
        #pragma unroll
        for (int rr = 0; rr < 4; rr++) {
            int sr = sr0 + rr * 16;
            const float* xp = x + (long)(row0 + sr) * INF_ + sc;
            float4 v0 = ((const float4*)xp)[0];
            float4 v1 = ((const float4*)xp)[1];
            float4 v2 = ((const float4*)xp)[2];
            float4 v3 = ((const float4*)xp)[3];
            ushort4 u0 = {f2bf(v0.x), f2bf(v0.y), f2bf(v0.z), f2bf(v0.w)};
            ushort4 u1 = {f2bf(v1.x), f2bf(v1.y), f2bf(v1.z), f2bf(v1.w)};
            ushort4 u2 = {f2bf(v2.x), f2bf(v2.y), f2bf(v2.z), f2bf(v2.w)};
            ushort4 u3 = {f2bf(v3.x), f2bf(v3.y), f2bf(v3.z), f2bf(v3.w)};
            *(ushort4*)&xls[sr][sc]      = u0;
            *(ushort4*)&xls[sr][sc + 4]  = u1;
            *(ushort4*)&xls[sr][sc + 8]  = u2;
            *(ushort4*)&xls[sr][sc + 12] = u3;
        }
    }
    __syncthreads();

    int wave = t >> 6, lane = t & 63, quad = lane >> 4, l15 = lane & 15;
    f32x4 acc[4][4];   // [rowgroup][nt] — all indices compile-time constant
    #pragma unroll
    for (int rg = 0; rg < 4; rg++)
        #pragma unroll
        for (int nt = 0; nt < 4; nt++) acc[rg][nt] = (f32x4){0.f, 0.f, 0.f, 0.f};

    #pragma unroll
    for (int ks = 0; ks < 8; ks++) {
        short8 bfr[4];
        #pragma unroll
        for (int nt = 0; nt < 4; nt++)
            bfr[nt] = *(const short8*)(wswz +
                ((long)((ks * 16 + wave * 4 + nt) * 64 + lane)) * 8);
        #pragma unroll
        for (int rg = 0; rg < 4; rg++) {
            short8 af = *(const short8*)&xls[rg * 16 + l15][ks * 32 + quad * 8];
            #pragma unroll
            for (int nt = 0; nt < 4; nt++)
                acc[rg][nt] = __builtin_amdgcn_mfma_f32_16x16x32_bf16(
                    af, bfr[nt], acc[rg][nt], 0, 0, 0);
        }
    }

    // hswz store (B-frag order for k_attn), per rowgroup
    int q0 = (quad & 1) * 4;
    #pragma unroll
    for (int rg = 0; rg < 4; rg++) {
        int row0g = row0 + rg * 16;
        int qd = ((row0g & 31) + quad * 4) >> 3;
        long bj32 = row0g >> 5;
        #pragma unroll
        for (int nt = 0; nt < 4; nt++) {
            int dg = wave * 4 + nt;
            long idx8 = (bj32 * 16 + dg) * 64 + qd * 16 + l15;
            ushort4 o = {f2bf(acc[rg][nt][0]), f2bf(acc[rg][nt][1]),
                         f2bf(acc[rg][nt][2]), f2bf(acc[rg][nt][3])};
            *(ushort4*)&hswz[idx8 * 8 + q0] = o;
        }
    }

    // fused scores -> row factor + exp pairs, pre-scaled by log2(e)
    float as_[4], ad_[4];
    #pragma unroll
    for (int nt = 0; nt < 4; nt++) {
        int d = nt * 16 + l15;
        as_[nt] = a[d * NH_ + wave];
        ad_[nt] = a[(64 + d) * NH_ + wave];
    }
    #pragma unroll
    for (int rg = 0; rg < 4; rg++) {
        #pragma unroll
        for (int r = 0; r < 4; r++) {
            float ps = acc[rg][0][r] * as_[0] + acc[rg][1][r] * as_[1]
                     + acc[rg][2][r] * as_[2] + acc[rg][3][r] * as_[3];
            float pd = acc[rg][0][r] * ad_[0] + acc[rg][1][r] * ad_[1]
                     + acc[rg][2][r] * ad_[2] + acc[rg][3][r] * ad_[3];
            #pragma unroll
            for (int m = 1; m < 16; m <<= 1) {
                ps += __shfl_xor(ps, m);
                pd += __shfl_xor(pd, m);
            }
            if (l15 == 0) {
                int row = n0 + rg * 16 + quad * 4 + r;
                float s1 = ps * L2E, s2 = pd * L2E;
                esr[((long)b * NH_ + wave) * N_ + row] = __builtin_exp2f(-0.8f * s1);
                edst[((long)b * NH_ + wave) * N_ + row] =
                    make_float2(__builtin_exp2f(s2), __builtin_exp2f(0.2f * s2));
            }
        }
    }
}

// ---------------------------------------------------------------------------
// Kernel C: masked softmax + MFMA aggregate — R13 (2-strip waves +
// head-grouped blocks + jh split + mask preload + hswz reg double-buffer;
// best measured) + SYMMETRIC EPILOGUE:
// Old epilogue: jh1 dumps 20 floats/lane, exits; jh0 alone combines and
// does ALL output stores (32 store-instr/lane) -> half the block idles a
// ~4-5us tail. New: each jh exchanges only the OTHER half's idt accs
// (12 floats/lane) and stores its own two idt columns — all 8 waves
// combine, all 8 store, store wall halves.
// accb[4][2][64][26]: per lane per jh-slot: strip0 {acc(8),dn(4)} @0,
// strip1 @13 (stride-13 halves, 26 total; 53KB; +esb 8KB = 61KB -> 2
// blocks/CU). All register arrays statically indexed (jh branches are
// wave-uniform, constant indices — rule-#20 safe).
// grid = 512 blocks (16b x 4h x 8 rowgroups of 128, XCD-swizzled) x 512
// thr = 8 waves = 4 strip-pairs (sp) x 2 jh. (512,4) ONLY.
// ---------------------------------------------------------------------------
__global__ __launch_bounds__(512, 4) void k_attn(
    const unsigned int* __restrict__ pb, const unsigned short* __restrict__ hswz,
    const float* __restrict__ esr, const float2* __restrict__ edst,
    float* __restrict__ out)
{
    __shared__ float2 esb[1024];               // 8 KB: edst slice for (b, hh)
    __shared__ uint2 mtab[16];
    __shared__ float accb[4][2][64][26];       // 53 KB [sp][jh][lane][2x13]

    int t = threadIdx.x;
    int bid = blockIdx.x;
    int swz = (bid & 7) * 64 + (bid >> 3);     // bijective (512 % 8 == 0)
    int b  = swz >> 5;                          // 2 b per XCD -> L2-resident
    int hh = (swz >> 3) & 3;
    int rg = swz & 7;
    int row0 = rg * 128;

    int wave = t >> 6, lane = t & 63, quad = lane >> 4, l15 = lane & 15;
    int sp = wave & 3, jh = wave >> 2;

    esb[t]       = edst[((long)(b * NH_ + hh)) * N_ + t];
    esb[t + 512] = edst[((long)(b * NH_ + hh)) * N_ + t + 512];
    if (t < 16) {
        int k = t;
        unsigned int w0 = ((k & 1) ? 0xffffu : 0u) | ((k & 2) ? 0xffff0000u : 0u);
        unsigned int w1 = ((k & 4) ? 0xffffu : 0u) | ((k & 8) ? 0xffff0000u : 0u);
        mtab[k] = make_uint2(w0, w1);
    }
    __syncthreads();

    int ir0 = row0 + sp * 32 + l15;            // strip0 row; strip1 = +16
    float r0 = esr[((long)(b * NH_ + hh)) * N_ + ir0];
    float r1 = esr[((long)(b * NH_ + hh)) * N_ + ir0 + 16];
    const unsigned int* pbw = pb + ((long)b << 10) + ir0;
    int shq = quad * 8;

    // ---- mask preload: 32 coalesced loads -> 8 packed VGPRs ----
    unsigned int mpk0[4], mpk1[4];
    #pragma unroll
    for (int g = 0; g < 4; g++) {
        unsigned int a0 = 0, a1 = 0;
        #pragma unroll
        for (int k = 0; k < 4; k++) {
            int w = jh * 16 + g * 4 + k;
            a0 |= ((pbw[(long)w << 14] >> shq) & 0xffu) << (8 * k);
            a1 |= ((pbw[((long)w << 14) + 16] >> shq) & 0xffu) << (8 * k);
        }
        mpk0[g] = a0; mpk1[g] = a1;
    }

    f32x4 acc0[4], acc1[4], dn0, dn1;
    #pragma unroll
    for (int i = 0; i < 4; i++) {
        acc0[i] = (f32x4){0.f, 0.f, 0.f, 0.f};
        acc1[i] = (f32x4){0.f, 0.f, 0.f, 0.f};
    }
    dn0 = (f32x4){0.f, 0.f, 0.f, 0.f};
    dn1 = (f32x4){0.f, 0.f, 0.f, 0.f};
    short8 ones;
    #pragma unroll
    for (int i = 0; i < 8; i++) ones[i] = (short)0x3F80;   // bf16 1.0

    // ---- hswz register double-buffer, prefetch distance 1 ----
    const unsigned short* hbase = hswz +
        (((long)(b * 32 + jh * 16)) * 1024 + (hh * 4) * 64 + lane) * 8;

    short8 bfA[4], bfB[4];
    #pragma unroll
    for (int idt = 0; idt < 4; idt++)
        bfA[idt] = *(const short8*)(hbase + idt * 512);

    #pragma unroll
    for (int jc = 0; jc < 16; jc += 2) {
        // prefetch jc+1 into bfB (off-chain)
        #pragma unroll
        for (int idt = 0; idt < 4; idt++)
            bfB[idt] = *(const short8*)(hbase + (long)(jc + 1) * 8192 + idt * 512);

        // weights for jc
        {
            int w = jh * 16 + jc;
            const f32x4* ej = (const f32x4*)&esb[w * 32 + quad * 8];
            union { unsigned int u[4]; short8 s; } p0, p1;
            #pragma unroll
            for (int qp = 0; qp < 4; qp++) {
                f32x4 d = ej[qp];   // {D1_j, D2_j, D1_j', D2_j'}
                p0.u[qp] = cvt_pk_bf16(fmaxf(d[0], r0 * d[1]), fmaxf(d[2], r0 * d[3]));
                p1.u[qp] = cvt_pk_bf16(fmaxf(d[0], r1 * d[1]), fmaxf(d[2], r1 * d[3]));
            }
            unsigned int m0 = (mpk0[jc >> 2] >> ((jc & 3) * 8)) & 0xffu;
            unsigned int m1 = (mpk1[jc >> 2] >> ((jc & 3) * 8)) & 0xffu;
            uint2 ma0 = mtab[m0 & 15u], mb0 = mtab[m0 >> 4];
            uint2 ma1 = mtab[m1 & 15u], mb1 = mtab[m1 >> 4];
            p0.u[0] &= ma0.x; p0.u[1] &= ma0.y; p0.u[2] &= mb0.x; p0.u[3] &= mb0.y;
            p1.u[0] &= ma1.x; p1.u[1] &= ma1.y; p1.u[2] &= mb1.x; p1.u[3] &= mb1.y;

            #pragma unroll
            for (int idt = 0; idt < 4; idt++) {
                acc0[idt] = __builtin_amdgcn_mfma_f32_16x16x32_bf16(p0.s, bfA[idt], acc0[idt], 0, 0, 0);
                acc1[idt] = __builtin_amdgcn_mfma_f32_16x16x32_bf16(p1.s, bfA[idt], acc1[idt], 0, 0, 0);
            }
            dn0 = __builtin_amdgcn_mfma_f32_16x16x32_bf16(p0.s, ones, dn0, 0, 0, 0);
            dn1 = __builtin_amdgcn_mfma_f32_16x16x32_bf16(p1.s, ones, dn1, 0, 0, 0);
        }

        // prefetch jc+2 into bfA (last iter: re-read jc+1, in-bounds, unused cost)
        {
            int wn = (jc + 2 < 16) ? jc + 2 : jc + 1;
            #pragma unroll
            for (int idt = 0; idt < 4; idt++)
                bfA[idt] = *(const short8*)(hbase + (long)wn * 8192 + idt * 512);
        }

        // weights for jc+1
        {
            int jd = jc + 1;
            int w = jh * 16 + jd;
            const f32x4* ej = (const f32x4*)&esb[w * 32 + quad * 8];
            union { unsigned int u[4]; short8 s; } p0, p1;
            #pragma unroll
            for (int qp = 0; qp < 4; qp++) {
                f32x4 d = ej[qp];
                p0.u[qp] = cvt_pk_bf16(fmaxf(d[0], r0 * d[1]), fmaxf(d[2], r0 * d[3]));
                p1.u[qp] = cvt_pk_bf16(fmaxf(d[0], r1 * d[1]), fmaxf(d[2], r1 * d[3]));
            }
            unsigned int m0 = (mpk0[jd >> 2] >> ((jd & 3) * 8)) & 0xffu;
            unsigned int m1 = (mpk1[jd >> 2] >> ((jd & 3) * 8)) & 0xffu;
            uint2 ma0 = mtab[m0 & 15u], mb0 = mtab[m0 >> 4];
            uint2 ma1 = mtab[m1 & 15u], mb1 = mtab[m1 >> 4];
            p0.u[0] &= ma0.x; p0.u[1] &= ma0.y; p0.u[2] &= mb0.x; p0.u[3] &= mb0.y;
            p1.u[0] &= ma1.x; p1.u[1] &= ma1.y; p1.u[2] &= mb1.x; p1.u[3] &= mb1.y;

            #pragma unroll
            for (int idt = 0; idt < 4; idt++) {
                acc0[idt] = __builtin_amdgcn_mfma_f32_16x16x32_bf16(p0.s, bfB[idt], acc0[idt], 0, 0, 0);
                acc1[idt] = __builtin_amdgcn_mfma_f32_16x16x32_bf16(p1.s, bfB[idt], acc1[idt], 0, 0, 0);
            }
            dn0 = __builtin_amdgcn_mfma_f32_16x16x32_bf16(p0.s, ones, dn0, 0, 0, 0);
            dn1 = __builtin_amdgcn_mfma_f32_16x16x32_bf16(p1.s, ones, dn1, 0, 0, 0);
        }
    }

    // ---- SYMMETRIC combine: each jh ships the half it does NOT store ----
    if (jh == 0) {
        // jh0 stores idt{0,1}; ships idt{2,3}
        *(f32x4*)&accb[sp][0][lane][0]  = acc0[2];
        *(f32x4*)&accb[sp][0][lane][4]  = acc0[3];
        *(f32x4*)&accb[sp][0][lane][8]  = dn0;
        *(f32x4*)&accb[sp][0][lane][13] = acc1[2];
        *(f32x4*)&accb[sp][0][lane][17] = acc1[3];
        *(f32x4*)&accb[sp][0][lane][21] = dn1;
    } else {
        // jh1 stores idt{2,3}; ships idt{0,1}
        *(f32x4*)&accb[sp][1][lane][0]  = acc0[0];
        *(f32x4*)&accb[sp][1][lane][4]  = acc0[1];
        *(f32x4*)&accb[sp][1][lane][8]  = dn0;
        *(f32x4*)&accb[sp][1][lane][13] = acc1[0];
        *(f32x4*)&accb[sp][1][lane][17] = acc1[1];
        *(f32x4*)&accb[sp][1][lane][21] = dn1;
    }
    __syncthreads();

    {
        int po = jh ^ 1;   // partner slot (LDS address arithmetic only)
        f32x4 q00 = *(const f32x4*)&accb[sp][po][lane][0];
        f32x4 q01 = *(const f32x4*)&accb[sp][po][lane][4];
        f32x4 qd0 = *(const f32x4*)&accb[sp][po][lane][8];
        f32x4 q10 = *(const f32x4*)&accb[sp][po][lane][13];
        f32x4 q11 = *(const f32x4*)&accb[sp][po][lane][17];
        f32x4 qd1 = *(const f32x4*)&accb[sp][po][lane][21];
        float inv0[4], inv1[4];
        #pragma unroll
        for (int r = 0; r < 4; r++) {
            inv0[r] = 1.0f / (dn0[r] + qd0[r]);
            inv1[r] = 1.0f / (dn1[r] + qd1[r]);
        }
        long rbase = (long)b * N_ + row0 + sp * 32 + quad * 4;
        if (jh == 0) {
            int c0 = hh * 64 + l15, c1 = c0 + 16;
            #pragma unroll
            for (int r = 0; r < 4; r++) {
                long rg0 = (rbase + r) * HD_, rg1 = (rbase + 16 + r) * HD_;
                out[rg0 + c0] = (acc0[0][r] + q00[r]) * inv0[r];
                out[rg0 + c1] = (acc0[1][r] + q01[r]) * inv0[r];
                out[rg1 + c0] = (acc1[0][r] + q10[r]) * inv1[r];
                out[rg1 + c1] = (acc1[1][r] + q11[r]) * inv1[r];
            }
        } else {
            int c2 = hh * 64 + 32 + l15, c3 = c2 + 16;
            #pragma unroll
            for (int r = 0; r < 4; r++) {
                long rg0 = (rbase + r) * HD_, rg1 = (rbase + 16 + r) * HD_;
                out[rg0 + c2] = (acc0[2][r] + q00[r]) * inv0[r];
                out[rg0 + c3] = (acc0[3][r] + q01[r]) * inv0[r];
                out[rg1 + c2] = (acc1[2][r] + q10[r]) * inv1[r];
                out[rg1 + c3] = (acc1[3][r] + q11[r]) * inv1[r];
            }
        }
    }
}

extern "C" void kernel_launch(void* const* d_in, const int* in_sizes, int n_in,
                              void* d_out, int out_size, void* d_ws, size_t ws_size,
                              hipStream_t stream) {
    const float* x   = (const float*)d_in[0];
    const int*   adj = (const int*)d_in[1];
    const float* W   = (const float*)d_in[2];
    const float* a   = (const float*)d_in[3];
    float* out = (float*)d_out;

    unsigned int* pb      = (unsigned int*)d_ws;                       // 2 MB
    unsigned short* hswz  = (unsigned short*)(pb + 524288);            // 8 MB
    unsigned short* wswz  = hswz + (long)B_ * N_ * HD_;                // 128 KB
    float* esr   = (float*)(wswz + INF_ * HD_);                        // 256 KB
    float2* edst = (float2*)(esr + (long)B_ * NH_ * N_);               // 512 KB

    k_prep<<<2080, 256, 0, stream>>>(adj, W, pb, wswz);
    k_gemm_h<<<256, 256, 0, stream>>>(x, a, wswz, hswz, esr, edst);
    k_attn<<<512, 512, 0, stream>>>(pb, hswz, esr, edst, out);
}